// Round 4
// baseline (2795.190 us; speedup 1.0000x reference)
//
#include <hip/hip_runtime.h>
#include <math.h>

#define NN 100000
#define EE 500000
#define ET 64
#define NPAD 500032          // 7813 * 64
#define NEB  7813

typedef __attribute__((ext_vector_type(8))) short short8;
typedef __attribute__((ext_vector_type(4))) float f32x4;

// LDS chunk swizzle: 16B chunks, XOR row&7 into chunk index (T2, §6 G4)
#define C32(row, ch) (((row)<<5) + ((ch) ^ ((row)&7)))           // [*][256] bf16 buffers
#define E32(row, col) ((C32((row),(col)>>3)<<3) + ((col)&7))

__device__ __forceinline__ f32x4 mfma16(short8 a, short8 b, f32x4 c){
    return __builtin_amdgcn_mfma_f32_16x16x32_bf16(a, b, c, 0, 0, 0);
}
__device__ __forceinline__ short f2bf(float f){
    union { float f; unsigned u; } v; v.f = f;
    unsigned r = v.u + 0x7fffu + ((v.u >> 16) & 1u);
    return (short)(r >> 16);
}
__device__ __forceinline__ float bf2f(short s){
    union { unsigned u; float f; } v; v.u = ((unsigned)(unsigned short)s) << 16;
    return v.f;
}
__device__ __forceinline__ short8 bfrag(const short* __restrict__ W, int K, int ct, int ks, int lane){
    return *(const short8*)(W + (long)(ct*16 + (lane&15))*K + ks*32 + (lane>>4)*8);
}
__device__ __forceinline__ float dot4f(float4 a, float4 b){
    return fmaf(a.x,b.x, fmaf(a.y,b.y, fmaf(a.z,b.z, a.w*b.w)));
}

// ---------------- Prep: convert all edge-stage weights to bf16 in ws ----------------
__global__ __launch_bounds__(256) void prep_kernel(
    const float* __restrict__ ent_w, const float* __restrict__ q_w,
    const float* __restrict__ k_w,   const float* __restrict__ v_w,
    const float* __restrict__ meas_w,const float* __restrict__ out_w,
    short* __restrict__ dst)
{
    int i = blockIdx.x*256 + threadIdx.x;   // 196608 total
    float v;
    if      (i <  65536) v = ent_w[i];
    else if (i <  81920) v = q_w[i-65536];
    else if (i <  98304) v = k_w[i-81920];
    else if (i < 114688) v = v_w[i-98304];
    else if (i < 180224) v = meas_w[i-114688];
    else                 v = out_w[i-180224];
    dst[i] = f2bf(v);
}

// ---------------- Sort pipeline: counting sort of edges by tgt ----------------
__global__ __launch_bounds__(256) void hist_kernel(const int* __restrict__ eidx, int* __restrict__ hist){
    int i = blockIdx.x*256 + threadIdx.x;
    if (i < EE) atomicAdd(&hist[eidx[EE+i]], 1);
}
__global__ __launch_bounds__(512) void scanA_kernel(const int* __restrict__ hist,
                                                    int* __restrict__ scanv, int* __restrict__ bsum){
    __shared__ int s[512];
    const int tid = threadIdx.x;
    const int i = blockIdx.x*512 + tid;
    int v = hist[i];
    s[tid] = v;
    __syncthreads();
    #pragma unroll
    for (int d=1; d<512; d<<=1){
        int t = (tid>=d) ? s[tid-d] : 0;
        __syncthreads();
        s[tid] += t;
        __syncthreads();
    }
    scanv[i] = s[tid] - v;
    if (tid==511) bsum[blockIdx.x] = s[511];
}
__global__ __launch_bounds__(256) void scanB_kernel(const int* __restrict__ bsum, int* __restrict__ boff){
    __shared__ int s[256];
    const int tid = threadIdx.x;
    int v = (tid<196) ? bsum[tid] : 0;
    s[tid] = v;
    __syncthreads();
    #pragma unroll
    for (int d=1; d<256; d<<=1){
        int t = (tid>=d) ? s[tid-d] : 0;
        __syncthreads();
        s[tid] += t;
        __syncthreads();
    }
    if (tid<196) boff[tid] = s[tid] - v;
}
__global__ __launch_bounds__(256) void scatter_kernel(const int* __restrict__ eidx,
    const int* __restrict__ scanv, const int* __restrict__ boff, int* __restrict__ cnt,
    int* __restrict__ sTgt, int* __restrict__ sSrc)
{
    int i = blockIdx.x*256 + threadIdx.x;
    if (i >= EE) return;
    int t = eidx[EE+i], sv = eidx[i];
    int r = atomicAdd(&cnt[t], 1);
    int pos = scanv[t] + boff[t>>9] + r;
    sTgt[pos] = t; sSrc[pos] = sv;
}

// ---------------- Stage 1: per-node quantum state prep -> qfb (N,128) bf16 ----------------
__global__ __launch_bounds__(256) void node_kernel(
    const float* __restrict__ x,
    const float* __restrict__ sp_w, const float* __restrict__ sp_b,
    const float* __restrict__ ln1_g, const float* __restrict__ ln1_b,
    const float* __restrict__ pg,
    const float* __restrict__ amp_w, const float* __restrict__ amp_b,
    const float* __restrict__ ph_w, const float* __restrict__ ph_b,
    short* __restrict__ qfb)
{
    const int tid = threadIdx.x;
    const int sub = tid >> 7;        // 2 nodes per block
    const int o   = tid & 127;
    const int n   = blockIdx.x*2 + sub;
    __shared__ float xr[2][128];
    __shared__ float qs[2][128];
    __shared__ float ap[2][128];
    __shared__ float red[4][2];

    if (o < 32) ((float4*)&xr[sub][0])[o] = ((const float4*)x)[(long)n*32 + o];
    __syncthreads();

    float acc = sp_b[o];
    {
        const float4* w4 = (const float4*)(sp_w + o*128);
        const float4* xv = (const float4*)&xr[sub][0];
        #pragma unroll
        for (int k=0;k<32;k++) acc += dot4f(w4[k], xv[k]);
    }
    float s = acc, sq = acc*acc;
    #pragma unroll
    for (int m=1;m<64;m<<=1){ s += __shfl_xor(s,m); sq += __shfl_xor(sq,m); }
    if ((tid&63)==0){ red[tid>>6][0]=s; red[tid>>6][1]=sq; }
    __syncthreads();
    float S  = red[sub*2][0]+red[sub*2+1][0];
    float SQ = red[sub*2][1]+red[sub*2+1][1];
    float mean = S*(1.0f/128.0f);
    float rstd = rsqrtf(SQ*(1.0f/128.0f)-mean*mean + 1e-5f);
    float qv = tanhf((acc-mean)*rstd*ln1_g[o] + ln1_b[o]);
    qs[sub][o] = qv;
    __syncthreads();

    const int o2 = o & 63;
    float a2;
    if (o < 64) {
        float r = amp_b[o2];
        const float4* w4 = (const float4*)(amp_w + o2*64);
        const float4* rv = (const float4*)&qs[sub][0];
        #pragma unroll
        for (int k=0;k<16;k++) r += dot4f(w4[k], rv[k]);
        a2 = 1.0f/(1.0f+expf(-r));
    } else {
        float r = ph_b[o2];
        const float4* w4 = (const float4*)(ph_w + o2*64);
        const float4* iv = (const float4*)&qs[sub][64];
        #pragma unroll
        for (int k=0;k<16;k++) r += dot4f(w4[k], iv[k]);
        a2 = tanhf(r)*3.14159265358979323846f;
    }
    ap[sub][o] = a2;
    __syncthreads();
    if (o < 64) {
        float amp = ap[sub][o];
        float ph  = ap[sub][64+o];
        float pgs = 0.f;
        #pragma unroll
        for (int r=0;r<8;r++) pgs += pg[r*64 + o];
        float ang = ph + qs[sub][o]*pgs;
        qfb[(long)n*128 + o]      = f2bf(amp * cosf(ang));
        qfb[(long)n*128 + 64 + o] = f2bf(amp * sinf(ang));
    }
}

// ---------------- Stage 2: per-edge MFMA message, tgt-sorted, LDS-reduced scatter ----------------
// Register-pressure discipline: no phase holds more than ~24 live f32 accumulators.
__global__ __launch_bounds__(512, 4) void edge_kernel(
    const short* __restrict__ qfb,
    const int* __restrict__ sTgt, const int* __restrict__ sSrc,
    const short* __restrict__ wE, const float* __restrict__ ent_b,
    const short* __restrict__ wQ, const float* __restrict__ q_b,
    const short* __restrict__ wK, const float* __restrict__ k_b,
    const short* __restrict__ wV, const float* __restrict__ v_b,
    const short* __restrict__ wM, const float* __restrict__ meas_b,
    const short* __restrict__ wO, const float* __restrict__ out_b,
    float* __restrict__ agg)
{
    __shared__ short xin[ET][256];                 // 32 KB: [xi|xj] bf16 swizzled; later msgb bf16 [64][128]
    __shared__ __align__(16) char bufB[ET*132*4];  // 33.8 KB: qkb/ebuf bf16 [64][256]; later msgF f32 stride 132
    __shared__ float swv[ET][4];
    __shared__ int tg[ET];
    __shared__ int srr[ET];
    __shared__ int tgPrevS, tgNextS;

    short* qk1  = (short*)bufB;
    float* msgF = (float*)bufB;

    // bijective XCD-chunked swizzle (m204): each XCD owns a contiguous tgt range
    const int nwg = gridDim.x, orig = blockIdx.x;
    const int qd = nwg>>3, rm = nwg&7, xc = orig&7, oo = orig>>3;
    const int bid = (xc<rm ? xc*(qd+1) : rm*(qd+1)+(xc-rm)*qd) + oo;

    const int tid  = threadIdx.x;
    const int lane = tid & 63;
    const int w    = tid >> 6;            // wave 0..7
    const long e0  = (long)bid * ET;
    const int l15  = lane & 15;
    const int lj   = (lane >> 4) << 2;

    if (tid < ET) { tg[tid] = sTgt[e0+tid]; srr[tid] = sSrc[e0+tid]; }
    if (tid == 64) tgPrevS = (e0 > 0)      ? sTgt[e0-1]  : -2;
    if (tid == 65) tgNextS = (e0+ET < NPAD)? sTgt[e0+ET] : -2;
    __syncthreads();

    // gather x_i (cols 0..127) / x_j (128..255), 16B chunks, swizzled store
    for (int t = tid; t < ET*32; t += 512) {
        int e = t >> 5, c8 = t & 31;
        int node = (c8 < 16) ? tg[e] : srr[e];
        if (node < 0) node = 0;            // padded rows -> harmless valid data
        short8 val = ((const short8*)(qfb + (long)node*128))[c8 & 15];
        ((short8*)&xin[0][0])[C32(e, c8)] = val;
    }
    __syncthreads();

    const short8* xinv = (const short8*)&xin[0][0];
    const int col = (w<<4) + l15;

    // ---- Phase Q: q = xi@Wq^T -> qkb bf16 (16 live accs) ----
    {
        f32x4 aq[4];
        #pragma unroll
        for (int r=0;r<4;r++) aq[r]=(f32x4){0,0,0,0};
        #pragma unroll
        for (int ks=0; ks<4; ks++){
            short8 bq = bfrag(wQ,128,w,ks,lane);
            #pragma unroll
            for (int r=0;r<4;r++)
                aq[r] = mfma16(xinv[C32(r*16+l15, (ks<<2)+(lane>>4))], bq, aq[r]);
        }
        float qbias = q_b[col];
        #pragma unroll
        for (int r=0;r<4;r++){
            #pragma unroll
            for (int j=0;j<4;j++)
                qk1[E32(r*16+lj+j, col)] = f2bf(aq[r][j] + qbias);
        }
    }
    // ---- Phase K: k = xj@Wk^T -> qkb bf16 ----
    {
        f32x4 ak[4];
        #pragma unroll
        for (int r=0;r<4;r++) ak[r]=(f32x4){0,0,0,0};
        #pragma unroll
        for (int ks=0; ks<4; ks++){
            short8 bk = bfrag(wK,128,w,ks,lane);
            #pragma unroll
            for (int r=0;r<4;r++)
                ak[r] = mfma16(xinv[C32(r*16+l15, 16+(ks<<2)+(lane>>4))], bk, ak[r]);
        }
        float kbias = k_b[col];
        #pragma unroll
        for (int r=0;r<4;r++){
            #pragma unroll
            for (int j=0;j<4;j++)
                qk1[E32(r*16+lj+j, 128+col)] = f2bf(ak[r][j] + kbias);
        }
    }
    __syncthreads();

    // ---- scores + softmax over 4 heads ----
    if (tid < 256){
        int e = tid >> 2, h = tid & 3;
        float s = 0.f;
        #pragma unroll
        for (int d=0; d<32; d++)
            s += bf2f(qk1[E32(e, h*32+d)]) * bf2f(qk1[E32(e, 128+h*32+d)]);
        swv[e][h] = s * 0.17677669529663688f;   // 1/sqrt(32)
    }
    __syncthreads();
    if (tid < ET){
        float s0=swv[tid][0], s1=swv[tid][1], s2=swv[tid][2], s3=swv[tid][3];
        float mx = fmaxf(fmaxf(s0,s1),fmaxf(s2,s3));
        s0=expf(s0-mx); s1=expf(s1-mx); s2=expf(s2-mx); s3=expf(s3-mx);
        float inv = 1.0f/(s0+s1+s2+s3);
        swv[tid][0]=s0*inv; swv[tid][1]=s1*inv; swv[tid][2]=s2*inv; swv[tid][3]=s3*inv;
    }
    __syncthreads();

    // ---- Phase ENT (two 16-col halves): ent = [xi|xj]@We^T -> overwrite qkb ----
    #pragma unroll 1
    for (int half=0; half<2; half++){
        const int ct = 2*w + half;
        f32x4 a0[4];
        #pragma unroll
        for (int r=0;r<4;r++) a0[r]=(f32x4){0,0,0,0};
        #pragma unroll
        for (int ks=0; ks<8; ks++){
            short8 b0 = bfrag(wE,256,ct,ks,lane);
            #pragma unroll
            for (int r=0;r<4;r++)
                a0[r] = mfma16(xinv[C32(r*16+l15, (ks<<2)+(lane>>4))], b0, a0[r]);
        }
        float bb = ent_b[ct*16 + l15];
        #pragma unroll
        for (int r=0;r<4;r++){
            #pragma unroll
            for (int j=0;j<4;j++)
                qk1[E32(r*16+lj+j, ct*16+l15)] = f2bf(a0[r][j] + bb);
        }
    }
    __syncthreads();

    // ---- Phase V: v = xj@Wv^T; qm = softmax_w * v (16 live accs) ----
    f32x4 qm[4];
    {
        #pragma unroll
        for (int r=0;r<4;r++) qm[r]=(f32x4){0,0,0,0};
        #pragma unroll
        for (int ks=0; ks<4; ks++){
            short8 bv = bfrag(wV,128,w,ks,lane);
            #pragma unroll
            for (int r=0;r<4;r++)
                qm[r] = mfma16(xinv[C32(r*16+l15, 16+(ks<<2)+(lane>>4))], bv, qm[r]);
        }
        float vbias = v_b[col];
        const int h = w >> 1;
        #pragma unroll
        for (int r=0;r<4;r++){
            #pragma unroll
            for (int j=0;j<4;j++)
                qm[r][j] = (qm[r][j] + vbias) * swv[r*16+lj+j][h];
        }
    }

    // ---- Phase MEAS: qm += mean_kk (ei@Wm^T+b)(ej@Wm^T+b); per-r mi/mj (8 live) ----
    {
        const short8* ebv = (const short8*)qk1;
        #pragma unroll 1
        for (int kk=0; kk<4; kk++){
            short8 bm[4];
            const short* wMk = wM + (long)kk*128*128;
            #pragma unroll
            for (int ks=0;ks<4;ks++) bm[ks] = bfrag(wMk, 128, w, ks, lane);
            float mb = meas_b[kk*128 + col];
            #pragma unroll
            for (int r=0;r<4;r++){
                f32x4 mi=(f32x4){0,0,0,0}, mj=(f32x4){0,0,0,0};
                #pragma unroll
                for (int ks=0;ks<4;ks++)
                    mi = mfma16(ebv[C32(r*16+l15, (ks<<2)+(lane>>4))], bm[ks], mi);
                #pragma unroll
                for (int ks=0;ks<4;ks++)
                    mj = mfma16(ebv[C32(r*16+l15, 16+(ks<<2)+(lane>>4))], bm[ks], mj);
                #pragma unroll
                for (int j=0;j<4;j++)
                    qm[r][j] += 0.25f*(mi[j]+mb)*(mj[j]+mb);
            }
        }
    }
    __syncthreads();   // xin reads (V) and qkb reads (MEAS) done

    // ---- write msg-in bf16 into msgb (overlaps xin) ----
    short* msgb = &xin[0][0];   // [64][128] swizzled (16-chunk variant)
    {
        #pragma unroll
        for (int r=0;r<4;r++){
            #pragma unroll
            for (int j=0;j<4;j++){
                int row = r*16 + lj + j;
                int ch = (col>>3) ^ (row&7);
                msgb[((row<<4)+ch)*8 + (col&7)] = f2bf(qm[r][j]);
            }
        }
    }
    __syncthreads();

    // ---- Phase OUT: msg = msgb@Wo^T + out_b -> msgF (f32, stride 132) ----
    {
        const short8* mv = (const short8*)msgb;
        f32x4 ao[4];
        #pragma unroll
        for (int r=0;r<4;r++) ao[r]=(f32x4){0,0,0,0};
        #pragma unroll
        for (int ks=0; ks<4; ks++){
            short8 bo = bfrag(wO,128,w,ks,lane);
            #pragma unroll
            for (int r=0;r<4;r++){
                int row = r*16+l15;
                int ch = ((ks<<2)+(lane>>4)) ^ (row&7);
                ao[r] = mfma16(mv[(row<<4)+ch], bo, ao[r]);
            }
        }
        float ob = out_b[col];
        #pragma unroll
        for (int r=0;r<4;r++){
            #pragma unroll
            for (int j=0;j<4;j++)
                msgF[(r*16+lj+j)*132 + col] = ao[r][j] + ob;
        }
    }
    __syncthreads();

    // ---- per-tile segmented reduction over sorted tgt runs ----
    if (tid < 128){
        const int c = tid;
        const int tgPrev = tgPrevS, tgNext = tgNextS;
        float acc = 0.f;
        int runStart = 0;
        #pragma unroll 1
        for (int r=0; r<ET; r++){
            acc += msgF[r*132 + c];
            bool last = (r==ET-1) || (tg[r+1] != tg[r]);
            if (last){
                int node = tg[r];
                if (node >= 0){
                    bool openL = (runStart==0) && (tgPrev == node);
                    bool openR = (r==ET-1)     && (tgNext == node);
                    if (openL || openR) atomicAdd(&agg[(long)node*128 + c], acc);
                    else                agg[(long)node*128 + c] = acc;
                }
                acc = 0.f; runStart = r+1;
            }
        }
    }
}

// ---------------- Stage 3: LN + exact gelu, in place on d_out ----------------
__global__ __launch_bounds__(256) void final_kernel(
    const float* __restrict__ g2, const float* __restrict__ b2,
    float* __restrict__ io)
{
    const int lane = threadIdx.x & 63;
    const int n = blockIdx.x*4 + (threadIdx.x>>6);
    float v0 = io[(long)n*128 + lane];
    float v1 = io[(long)n*128 + 64 + lane];
    float s = v0+v1, sq = v0*v0 + v1*v1;
    #pragma unroll
    for (int m=1;m<64;m<<=1){ s += __shfl_xor(s,m); sq += __shfl_xor(sq,m); }
    float mean = s*(1.0f/128.0f);
    float rstd = rsqrtf(sq*(1.0f/128.0f)-mean*mean+1e-5f);
    float y0 = (v0-mean)*rstd*g2[lane]    + b2[lane];
    float y1 = (v1-mean)*rstd*g2[64+lane] + b2[64+lane];
    io[(long)n*128+lane]    = 0.5f*y0*(1.0f+erff(y0*0.70710678118f));
    io[(long)n*128+64+lane] = 0.5f*y1*(1.0f+erff(y1*0.70710678118f));
}

extern "C" void kernel_launch(void* const* d_in, const int* in_sizes, int n_in,
                              void* d_out, int out_size, void* d_ws, size_t ws_size,
                              hipStream_t stream)
{
    const float* x      = (const float*)d_in[0];
    const int*   eidx   = (const int*)  d_in[1];
    const float* sp_w   = (const float*)d_in[2];
    const float* sp_b   = (const float*)d_in[3];
    const float* ln1_g  = (const float*)d_in[4];
    const float* ln1_b  = (const float*)d_in[5];
    const float* pg     = (const float*)d_in[6];
    const float* amp_w  = (const float*)d_in[7];
    const float* amp_b  = (const float*)d_in[8];
    const float* ph_w   = (const float*)d_in[9];
    const float* ph_b   = (const float*)d_in[10];
    const float* ent_w  = (const float*)d_in[11];
    const float* ent_b  = (const float*)d_in[12];
    const float* q_w    = (const float*)d_in[13];
    const float* q_b    = (const float*)d_in[14];
    const float* k_w    = (const float*)d_in[15];
    const float* k_b    = (const float*)d_in[16];
    const float* v_w    = (const float*)d_in[17];
    const float* v_b    = (const float*)d_in[18];
    const float* meas_w = (const float*)d_in[19];
    const float* meas_b = (const float*)d_in[20];
    const float* out_w  = (const float*)d_in[21];
    const float* out_b  = (const float*)d_in[22];
    const float* ln2_g  = (const float*)d_in[23];
    const float* ln2_b  = (const float*)d_in[24];

    char* wsb = (char*)d_ws;
    short* qfb  = (short*)wsb;                      // 25,600,000 B
    short* wAll = (short*)(wsb + 25600000);         //    393,216 B
    int* hist   = (int*)(wsb + 25993216);           //    401,408 B (100352 bins)
    int* cnt    = (int*)(wsb + 26394624);           //    401,408 B
    int* scanv  = (int*)(wsb + 26796032);           //    401,408 B
    int* bsum   = (int*)(wsb + 27197440);           //      1,024 B
    int* boff   = (int*)(wsb + 27198464);           //      1,024 B
    int* sTgt   = (int*)(wsb + 27199488);           //  2,000,128 B
    int* sSrc   = (int*)(wsb + 29199616);           //  2,000,128 B  -> 31.2 MB

    short* wE = wAll;                               // 256*256
    short* wQ = wE + 65536;                         // 128*128
    short* wK = wQ + 16384;
    short* wV = wK + 16384;
    short* wM = wV + 16384;                         // 4*128*128
    short* wO = wM + 65536;

    float* agg = (float*)d_out;

    hipMemsetAsync(d_out, 0, (size_t)NN*128*sizeof(float), stream);
    hipMemsetAsync(hist, 0, 401408, stream);
    hipMemsetAsync(cnt,  0, 401408, stream);
    hipMemsetAsync(sTgt + EE, 0xFF, (NPAD-EE)*sizeof(int), stream);   // pad tgt = -1
    hipMemsetAsync(sSrc + EE, 0x00, (NPAD-EE)*sizeof(int), stream);   // pad src = 0

    prep_kernel<<<768, 256, 0, stream>>>(ent_w, q_w, k_w, v_w, meas_w, out_w, wAll);
    node_kernel<<<NN/2, 256, 0, stream>>>(x, sp_w, sp_b, ln1_g, ln1_b, pg,
                                          amp_w, amp_b, ph_w, ph_b, qfb);
    hist_kernel<<<(EE+255)/256, 256, 0, stream>>>(eidx, hist);
    scanA_kernel<<<196, 512, 0, stream>>>(hist, scanv, bsum);
    scanB_kernel<<<1, 256, 0, stream>>>(bsum, boff);
    scatter_kernel<<<(EE+255)/256, 256, 0, stream>>>(eidx, scanv, boff, cnt, sTgt, sSrc);
    edge_kernel<<<NEB, 512, 0, stream>>>(qfb, sTgt, sSrc,
                                         wE, ent_b, wQ, q_b, wK, k_b, wV, v_b,
                                         wM, meas_b, wO, out_b, agg);
    final_kernel<<<NN/4, 256, 0, stream>>>(ln2_g, ln2_b, agg);
}

// Round 5
// 1875.179 us; speedup vs baseline: 1.4906x; 1.4906x over previous
//
#include <hip/hip_runtime.h>
#include <math.h>

#define NN 100000
#define EE 500000
#define ET 64
#define NPAD 500032          // 7813 * 64
#define NEB  7813

typedef __attribute__((ext_vector_type(8))) short short8;
typedef __attribute__((ext_vector_type(4))) float f32x4;

// LDS chunk swizzle: 16B chunks, XOR row&7 into chunk index (T2, §6 G4)
#define C32(row, ch) (((row)<<5) + ((ch) ^ ((row)&7)))           // [*][256] bf16 buffers
#define E32(row, col) ((C32((row),(col)>>3)<<3) + ((col)&7))

__device__ __forceinline__ f32x4 mfma16(short8 a, short8 b, f32x4 c){
    return __builtin_amdgcn_mfma_f32_16x16x32_bf16(a, b, c, 0, 0, 0);
}
__device__ __forceinline__ short f2bf(float f){
    union { float f; unsigned u; } v; v.f = f;
    unsigned r = v.u + 0x7fffu + ((v.u >> 16) & 1u);
    return (short)(r >> 16);
}
__device__ __forceinline__ float bf2f(short s){
    union { unsigned u; float f; } v; v.u = ((unsigned)(unsigned short)s) << 16;
    return v.f;
}
__device__ __forceinline__ short8 bfrag(const short* __restrict__ W, int K, int ct, int ks, int lane){
    return *(const short8*)(W + (long)(ct*16 + (lane&15))*K + ks*32 + (lane>>4)*8);
}
__device__ __forceinline__ float dot4f(float4 a, float4 b){
    return fmaf(a.x,b.x, fmaf(a.y,b.y, fmaf(a.z,b.z, a.w*b.w)));
}

// ---------------- Prep: convert all edge-stage weights to bf16 in ws ----------------
__global__ __launch_bounds__(256) void prep_kernel(
    const float* __restrict__ ent_w, const float* __restrict__ q_w,
    const float* __restrict__ k_w,   const float* __restrict__ v_w,
    const float* __restrict__ meas_w,const float* __restrict__ out_w,
    short* __restrict__ dst)
{
    int i = blockIdx.x*256 + threadIdx.x;   // 196608 total
    float v;
    if      (i <  65536) v = ent_w[i];
    else if (i <  81920) v = q_w[i-65536];
    else if (i <  98304) v = k_w[i-81920];
    else if (i < 114688) v = v_w[i-98304];
    else if (i < 180224) v = meas_w[i-114688];
    else                 v = out_w[i-180224];
    dst[i] = f2bf(v);
}

// ---------------- Sort pipeline: counting sort of edges by tgt ----------------
__global__ __launch_bounds__(256) void hist_kernel(const int* __restrict__ eidx, int* __restrict__ hist){
    int i = blockIdx.x*256 + threadIdx.x;
    if (i < EE) atomicAdd(&hist[eidx[EE+i]], 1);
}
__global__ __launch_bounds__(512) void scanA_kernel(const int* __restrict__ hist,
                                                    int* __restrict__ scanv, int* __restrict__ bsum){
    __shared__ int s[512];
    const int tid = threadIdx.x;
    const int i = blockIdx.x*512 + tid;
    int v = hist[i];
    s[tid] = v;
    __syncthreads();
    #pragma unroll
    for (int d=1; d<512; d<<=1){
        int t = (tid>=d) ? s[tid-d] : 0;
        __syncthreads();
        s[tid] += t;
        __syncthreads();
    }
    scanv[i] = s[tid] - v;
    if (tid==511) bsum[blockIdx.x] = s[511];
}
__global__ __launch_bounds__(256) void scanB_kernel(const int* __restrict__ bsum, int* __restrict__ boff){
    __shared__ int s[256];
    const int tid = threadIdx.x;
    int v = (tid<196) ? bsum[tid] : 0;
    s[tid] = v;
    __syncthreads();
    #pragma unroll
    for (int d=1; d<256; d<<=1){
        int t = (tid>=d) ? s[tid-d] : 0;
        __syncthreads();
        s[tid] += t;
        __syncthreads();
    }
    if (tid<196) boff[tid] = s[tid] - v;
}
__global__ __launch_bounds__(256) void scatter_kernel(const int* __restrict__ eidx,
    const int* __restrict__ scanv, const int* __restrict__ boff, int* __restrict__ cnt,
    int* __restrict__ sTgt, int* __restrict__ sSrc)
{
    int i = blockIdx.x*256 + threadIdx.x;
    if (i >= EE) return;
    int t = eidx[EE+i], sv = eidx[i];
    int r = atomicAdd(&cnt[t], 1);
    int pos = scanv[t] + boff[t>>9] + r;
    sTgt[pos] = t; sSrc[pos] = sv;
}

// ---------------- Stage 1: per-node quantum state prep -> qfb (N,128) bf16 ----------------
__global__ __launch_bounds__(256) void node_kernel(
    const float* __restrict__ x,
    const float* __restrict__ sp_w, const float* __restrict__ sp_b,
    const float* __restrict__ ln1_g, const float* __restrict__ ln1_b,
    const float* __restrict__ pg,
    const float* __restrict__ amp_w, const float* __restrict__ amp_b,
    const float* __restrict__ ph_w, const float* __restrict__ ph_b,
    short* __restrict__ qfb)
{
    const int tid = threadIdx.x;
    const int sub = tid >> 7;        // 2 nodes per block
    const int o   = tid & 127;
    const int n   = blockIdx.x*2 + sub;
    __shared__ float xr[2][128];
    __shared__ float qs[2][128];
    __shared__ float ap[2][128];
    __shared__ float red[4][2];

    if (o < 32) ((float4*)&xr[sub][0])[o] = ((const float4*)x)[(long)n*32 + o];
    __syncthreads();

    float acc = sp_b[o];
    {
        const float4* w4 = (const float4*)(sp_w + o*128);
        const float4* xv = (const float4*)&xr[sub][0];
        #pragma unroll
        for (int k=0;k<32;k++) acc += dot4f(w4[k], xv[k]);
    }
    float s = acc, sq = acc*acc;
    #pragma unroll
    for (int m=1;m<64;m<<=1){ s += __shfl_xor(s,m); sq += __shfl_xor(sq,m); }
    if ((tid&63)==0){ red[tid>>6][0]=s; red[tid>>6][1]=sq; }
    __syncthreads();
    float S  = red[sub*2][0]+red[sub*2+1][0];
    float SQ = red[sub*2][1]+red[sub*2+1][1];
    float mean = S*(1.0f/128.0f);
    float rstd = rsqrtf(SQ*(1.0f/128.0f)-mean*mean + 1e-5f);
    float qv = tanhf((acc-mean)*rstd*ln1_g[o] + ln1_b[o]);
    qs[sub][o] = qv;
    __syncthreads();

    const int o2 = o & 63;
    float a2;
    if (o < 64) {
        float r = amp_b[o2];
        const float4* w4 = (const float4*)(amp_w + o2*64);
        const float4* rv = (const float4*)&qs[sub][0];
        #pragma unroll
        for (int k=0;k<16;k++) r += dot4f(w4[k], rv[k]);
        a2 = 1.0f/(1.0f+expf(-r));
    } else {
        float r = ph_b[o2];
        const float4* w4 = (const float4*)(ph_w + o2*64);
        const float4* iv = (const float4*)&qs[sub][64];
        #pragma unroll
        for (int k=0;k<16;k++) r += dot4f(w4[k], iv[k]);
        a2 = tanhf(r)*3.14159265358979323846f;
    }
    ap[sub][o] = a2;
    __syncthreads();
    if (o < 64) {
        float amp = ap[sub][o];
        float ph  = ap[sub][64+o];
        float pgs = 0.f;
        #pragma unroll
        for (int r=0;r<8;r++) pgs += pg[r*64 + o];
        float ang = ph + qs[sub][o]*pgs;
        qfb[(long)n*128 + o]      = f2bf(amp * cosf(ang));
        qfb[(long)n*128 + 64 + o] = f2bf(amp * sinf(ang));
    }
}

// ---------------- Stage 2: per-edge MFMA message, tgt-sorted, LDS-reduced scatter ----------------
// NOTE: no min-occupancy arg on launch_bounds — 512 threads => VGPR cap 256.
// The (512,4) clamp forced VGPR=64 and spilled ~5.5 GB/dispatch to scratch (rounds 2-4).
__global__ __launch_bounds__(512) void edge_kernel(
    const short* __restrict__ qfb,
    const int* __restrict__ sTgt, const int* __restrict__ sSrc,
    const short* __restrict__ wE, const float* __restrict__ ent_b,
    const short* __restrict__ wQ, const float* __restrict__ q_b,
    const short* __restrict__ wK, const float* __restrict__ k_b,
    const short* __restrict__ wV, const float* __restrict__ v_b,
    const short* __restrict__ wM, const float* __restrict__ meas_b,
    const short* __restrict__ wO, const float* __restrict__ out_b,
    float* __restrict__ agg)
{
    __shared__ short xin[ET][256];                 // 32 KB: [xi|xj] bf16 swizzled; later msgb bf16 [64][128]
    __shared__ __align__(16) char bufB[ET*132*4];  // 33.8 KB: qkb/ebuf bf16 [64][256]; later msgF f32 stride 132
    __shared__ float swv[ET][4];
    __shared__ int tg[ET];
    __shared__ int srr[ET];
    __shared__ int tgPrevS, tgNextS;

    short* qk1  = (short*)bufB;
    float* msgF = (float*)bufB;

    // bijective XCD-chunked swizzle (m204): each XCD owns a contiguous tgt range
    const int nwg = gridDim.x, orig = blockIdx.x;
    const int qd = nwg>>3, rm = nwg&7, xc = orig&7, oo = orig>>3;
    const int bid = (xc<rm ? xc*(qd+1) : rm*(qd+1)+(xc-rm)*qd) + oo;

    const int tid  = threadIdx.x;
    const int lane = tid & 63;
    const int w    = tid >> 6;            // wave 0..7
    const long e0  = (long)bid * ET;
    const int l15  = lane & 15;
    const int lj   = (lane >> 4) << 2;

    if (tid < ET) { tg[tid] = sTgt[e0+tid]; srr[tid] = sSrc[e0+tid]; }
    if (tid == 64) tgPrevS = (e0 > 0)      ? sTgt[e0-1]  : -2;
    if (tid == 65) tgNextS = (e0+ET < NPAD)? sTgt[e0+ET] : -2;
    __syncthreads();

    // gather x_i (cols 0..127) / x_j (128..255), 16B chunks, swizzled store
    for (int t = tid; t < ET*32; t += 512) {
        int e = t >> 5, c8 = t & 31;
        int node = (c8 < 16) ? tg[e] : srr[e];
        if (node < 0) node = 0;            // padded rows -> harmless valid data
        short8 val = ((const short8*)(qfb + (long)node*128))[c8 & 15];
        ((short8*)&xin[0][0])[C32(e, c8)] = val;
    }
    __syncthreads();

    const short8* xinv = (const short8*)&xin[0][0];
    const int col = (w<<4) + l15;

    // ---- Phase Q: q = xi@Wq^T -> qkb bf16 (16 live accs) ----
    {
        f32x4 aq[4];
        #pragma unroll
        for (int r=0;r<4;r++) aq[r]=(f32x4){0,0,0,0};
        #pragma unroll
        for (int ks=0; ks<4; ks++){
            short8 bq = bfrag(wQ,128,w,ks,lane);
            #pragma unroll
            for (int r=0;r<4;r++)
                aq[r] = mfma16(xinv[C32(r*16+l15, (ks<<2)+(lane>>4))], bq, aq[r]);
        }
        float qbias = q_b[col];
        #pragma unroll
        for (int r=0;r<4;r++){
            #pragma unroll
            for (int j=0;j<4;j++)
                qk1[E32(r*16+lj+j, col)] = f2bf(aq[r][j] + qbias);
        }
    }
    // ---- Phase K: k = xj@Wk^T -> qkb bf16 ----
    {
        f32x4 ak[4];
        #pragma unroll
        for (int r=0;r<4;r++) ak[r]=(f32x4){0,0,0,0};
        #pragma unroll
        for (int ks=0; ks<4; ks++){
            short8 bk = bfrag(wK,128,w,ks,lane);
            #pragma unroll
            for (int r=0;r<4;r++)
                ak[r] = mfma16(xinv[C32(r*16+l15, 16+(ks<<2)+(lane>>4))], bk, ak[r]);
        }
        float kbias = k_b[col];
        #pragma unroll
        for (int r=0;r<4;r++){
            #pragma unroll
            for (int j=0;j<4;j++)
                qk1[E32(r*16+lj+j, 128+col)] = f2bf(ak[r][j] + kbias);
        }
    }
    __syncthreads();

    // ---- scores + softmax over 4 heads ----
    if (tid < 256){
        int e = tid >> 2, h = tid & 3;
        float s = 0.f;
        #pragma unroll
        for (int d=0; d<32; d++)
            s += bf2f(qk1[E32(e, h*32+d)]) * bf2f(qk1[E32(e, 128+h*32+d)]);
        swv[e][h] = s * 0.17677669529663688f;   // 1/sqrt(32)
    }
    __syncthreads();
    if (tid < ET){
        float s0=swv[tid][0], s1=swv[tid][1], s2=swv[tid][2], s3=swv[tid][3];
        float mx = fmaxf(fmaxf(s0,s1),fmaxf(s2,s3));
        s0=expf(s0-mx); s1=expf(s1-mx); s2=expf(s2-mx); s3=expf(s3-mx);
        float inv = 1.0f/(s0+s1+s2+s3);
        swv[tid][0]=s0*inv; swv[tid][1]=s1*inv; swv[tid][2]=s2*inv; swv[tid][3]=s3*inv;
    }
    __syncthreads();

    // ---- Phase ENT (two 16-col halves): ent = [xi|xj]@We^T -> overwrite qkb ----
    #pragma unroll 1
    for (int half=0; half<2; half++){
        const int ct = 2*w + half;
        f32x4 a0[4];
        #pragma unroll
        for (int r=0;r<4;r++) a0[r]=(f32x4){0,0,0,0};
        #pragma unroll
        for (int ks=0; ks<8; ks++){
            short8 b0 = bfrag(wE,256,ct,ks,lane);
            #pragma unroll
            for (int r=0;r<4;r++)
                a0[r] = mfma16(xinv[C32(r*16+l15, (ks<<2)+(lane>>4))], b0, a0[r]);
        }
        float bb = ent_b[ct*16 + l15];
        #pragma unroll
        for (int r=0;r<4;r++){
            #pragma unroll
            for (int j=0;j<4;j++)
                qk1[E32(r*16+lj+j, ct*16+l15)] = f2bf(a0[r][j] + bb);
        }
    }
    __syncthreads();

    // ---- Phase V: v = xj@Wv^T; qm = softmax_w * v (16 live accs) ----
    f32x4 qm[4];
    {
        #pragma unroll
        for (int r=0;r<4;r++) qm[r]=(f32x4){0,0,0,0};
        #pragma unroll
        for (int ks=0; ks<4; ks++){
            short8 bv = bfrag(wV,128,w,ks,lane);
            #pragma unroll
            for (int r=0;r<4;r++)
                qm[r] = mfma16(xinv[C32(r*16+l15, 16+(ks<<2)+(lane>>4))], bv, qm[r]);
        }
        float vbias = v_b[col];
        const int h = w >> 1;
        #pragma unroll
        for (int r=0;r<4;r++){
            #pragma unroll
            for (int j=0;j<4;j++)
                qm[r][j] = (qm[r][j] + vbias) * swv[r*16+lj+j][h];
        }
    }

    // ---- Phase MEAS: qm += mean_kk (ei@Wm^T+b)(ej@Wm^T+b); per-r mi/mj (8 live) ----
    {
        const short8* ebv = (const short8*)qk1;
        #pragma unroll 1
        for (int kk=0; kk<4; kk++){
            short8 bm[4];
            const short* wMk = wM + (long)kk*128*128;
            #pragma unroll
            for (int ks=0;ks<4;ks++) bm[ks] = bfrag(wMk, 128, w, ks, lane);
            float mb = meas_b[kk*128 + col];
            #pragma unroll
            for (int r=0;r<4;r++){
                f32x4 mi=(f32x4){0,0,0,0}, mj=(f32x4){0,0,0,0};
                #pragma unroll
                for (int ks=0;ks<4;ks++)
                    mi = mfma16(ebv[C32(r*16+l15, (ks<<2)+(lane>>4))], bm[ks], mi);
                #pragma unroll
                for (int ks=0;ks<4;ks++)
                    mj = mfma16(ebv[C32(r*16+l15, 16+(ks<<2)+(lane>>4))], bm[ks], mj);
                #pragma unroll
                for (int j=0;j<4;j++)
                    qm[r][j] += 0.25f*(mi[j]+mb)*(mj[j]+mb);
            }
        }
    }
    __syncthreads();   // xin reads (V) and qkb reads (MEAS) done

    // ---- write msg-in bf16 into msgb (overlaps xin) ----
    short* msgb = &xin[0][0];   // [64][128] swizzled (16-chunk variant)
    {
        #pragma unroll
        for (int r=0;r<4;r++){
            #pragma unroll
            for (int j=0;j<4;j++){
                int row = r*16 + lj + j;
                int ch = (col>>3) ^ (row&7);
                msgb[((row<<4)+ch)*8 + (col&7)] = f2bf(qm[r][j]);
            }
        }
    }
    __syncthreads();

    // ---- Phase OUT: msg = msgb@Wo^T + out_b -> msgF (f32, stride 132) ----
    {
        const short8* mv = (const short8*)msgb;
        f32x4 ao[4];
        #pragma unroll
        for (int r=0;r<4;r++) ao[r]=(f32x4){0,0,0,0};
        #pragma unroll
        for (int ks=0; ks<4; ks++){
            short8 bo = bfrag(wO,128,w,ks,lane);
            #pragma unroll
            for (int r=0;r<4;r++){
                int row = r*16+l15;
                int ch = ((ks<<2)+(lane>>4)) ^ (row&7);
                ao[r] = mfma16(mv[(row<<4)+ch], bo, ao[r]);
            }
        }
        float ob = out_b[col];
        #pragma unroll
        for (int r=0;r<4;r++){
            #pragma unroll
            for (int j=0;j<4;j++)
                msgF[(r*16+lj+j)*132 + col] = ao[r][j] + ob;
        }
    }
    __syncthreads();

    // ---- per-tile segmented reduction over sorted tgt runs ----
    if (tid < 128){
        const int c = tid;
        const int tgPrev = tgPrevS, tgNext = tgNextS;
        float acc = 0.f;
        int runStart = 0;
        #pragma unroll 1
        for (int r=0; r<ET; r++){
            acc += msgF[r*132 + c];
            bool last = (r==ET-1) || (tg[r+1] != tg[r]);
            if (last){
                int node = tg[r];
                if (node >= 0){
                    bool openL = (runStart==0) && (tgPrev == node);
                    bool openR = (r==ET-1)     && (tgNext == node);
                    if (openL || openR) atomicAdd(&agg[(long)node*128 + c], acc);
                    else                agg[(long)node*128 + c] = acc;
                }
                acc = 0.f; runStart = r+1;
            }
        }
    }
}

// ---------------- Stage 3: LN + exact gelu, in place on d_out ----------------
__global__ __launch_bounds__(256) void final_kernel(
    const float* __restrict__ g2, const float* __restrict__ b2,
    float* __restrict__ io)
{
    const int lane = threadIdx.x & 63;
    const int n = blockIdx.x*4 + (threadIdx.x>>6);
    float v0 = io[(long)n*128 + lane];
    float v1 = io[(long)n*128 + 64 + lane];
    float s = v0+v1, sq = v0*v0 + v1*v1;
    #pragma unroll
    for (int m=1;m<64;m<<=1){ s += __shfl_xor(s,m); sq += __shfl_xor(sq,m); }
    float mean = s*(1.0f/128.0f);
    float rstd = rsqrtf(sq*(1.0f/128.0f)-mean*mean+1e-5f);
    float y0 = (v0-mean)*rstd*g2[lane]    + b2[lane];
    float y1 = (v1-mean)*rstd*g2[64+lane] + b2[64+lane];
    io[(long)n*128+lane]    = 0.5f*y0*(1.0f+erff(y0*0.70710678118f));
    io[(long)n*128+64+lane] = 0.5f*y1*(1.0f+erff(y1*0.70710678118f));
}

extern "C" void kernel_launch(void* const* d_in, const int* in_sizes, int n_in,
                              void* d_out, int out_size, void* d_ws, size_t ws_size,
                              hipStream_t stream)
{
    const float* x      = (const float*)d_in[0];
    const int*   eidx   = (const int*)  d_in[1];
    const float* sp_w   = (const float*)d_in[2];
    const float* sp_b   = (const float*)d_in[3];
    const float* ln1_g  = (const float*)d_in[4];
    const float* ln1_b  = (const float*)d_in[5];
    const float* pg     = (const float*)d_in[6];
    const float* amp_w  = (const float*)d_in[7];
    const float* amp_b  = (const float*)d_in[8];
    const float* ph_w   = (const float*)d_in[9];
    const float* ph_b   = (const float*)d_in[10];
    const float* ent_w  = (const float*)d_in[11];
    const float* ent_b  = (const float*)d_in[12];
    const float* q_w    = (const float*)d_in[13];
    const float* q_b    = (const float*)d_in[14];
    const float* k_w    = (const float*)d_in[15];
    const float* k_b    = (const float*)d_in[16];
    const float* v_w    = (const float*)d_in[17];
    const float* v_b    = (const float*)d_in[18];
    const float* meas_w = (const float*)d_in[19];
    const float* meas_b = (const float*)d_in[20];
    const float* out_w  = (const float*)d_in[21];
    const float* out_b  = (const float*)d_in[22];
    const float* ln2_g  = (const float*)d_in[23];
    const float* ln2_b  = (const float*)d_in[24];

    char* wsb = (char*)d_ws;
    short* qfb  = (short*)wsb;                      // 25,600,000 B
    short* wAll = (short*)(wsb + 25600000);         //    393,216 B
    int* hist   = (int*)(wsb + 25993216);           //    401,408 B (100352 bins)
    int* cnt    = (int*)(wsb + 26394624);           //    401,408 B
    int* scanv  = (int*)(wsb + 26796032);           //    401,408 B
    int* bsum   = (int*)(wsb + 27197440);           //      1,024 B
    int* boff   = (int*)(wsb + 27198464);           //      1,024 B
    int* sTgt   = (int*)(wsb + 27199488);           //  2,000,128 B
    int* sSrc   = (int*)(wsb + 29199616);           //  2,000,128 B  -> 31.2 MB

    short* wE = wAll;                               // 256*256
    short* wQ = wE + 65536;                         // 128*128
    short* wK = wQ + 16384;
    short* wV = wK + 16384;
    short* wM = wV + 16384;                         // 4*128*128
    short* wO = wM + 65536;

    float* agg = (float*)d_out;

    hipMemsetAsync(d_out, 0, (size_t)NN*128*sizeof(float), stream);
    hipMemsetAsync(hist, 0, 401408, stream);
    hipMemsetAsync(cnt,  0, 401408, stream);
    hipMemsetAsync(sTgt + EE, 0xFF, (NPAD-EE)*sizeof(int), stream);   // pad tgt = -1
    hipMemsetAsync(sSrc + EE, 0x00, (NPAD-EE)*sizeof(int), stream);   // pad src = 0

    prep_kernel<<<768, 256, 0, stream>>>(ent_w, q_w, k_w, v_w, meas_w, out_w, wAll);
    node_kernel<<<NN/2, 256, 0, stream>>>(x, sp_w, sp_b, ln1_g, ln1_b, pg,
                                          amp_w, amp_b, ph_w, ph_b, qfb);
    hist_kernel<<<(EE+255)/256, 256, 0, stream>>>(eidx, hist);
    scanA_kernel<<<196, 512, 0, stream>>>(hist, scanv, bsum);
    scanB_kernel<<<1, 256, 0, stream>>>(bsum, boff);
    scatter_kernel<<<(EE+255)/256, 256, 0, stream>>>(eidx, scanv, boff, cnt, sTgt, sSrc);
    edge_kernel<<<NEB, 512, 0, stream>>>(qfb, sTgt, sSrc,
                                         wE, ent_b, wQ, q_b, wK, k_b, wV, v_b,
                                         wM, meas_b, wO, out_b, agg);
    final_kernel<<<NN/4, 256, 0, stream>>>(ln2_g, ln2_b, agg);
}

// Round 6
// 903.466 us; speedup vs baseline: 3.0939x; 2.0755x over previous
//
#include <hip/hip_runtime.h>
#include <math.h>

#define NN 100000
#define EE 500000
#define ET 64
#define NPAD 500032          // 7813 * 64
#define NEB  7813
#define NNB  1563            // ceil(100000/64)

typedef __attribute__((ext_vector_type(8))) short short8;
typedef __attribute__((ext_vector_type(4))) float f32x4;

// LDS chunk swizzle: 16B chunks, XOR row&7 into chunk index (T2, §6 G4)
#define C32(row, ch) (((row)<<5) + ((ch) ^ ((row)&7)))           // [*][256] bf16 buffers
#define E32(row, col) ((C32((row),(col)>>3)<<3) + ((col)&7))
#define C16(row, ch) (((row)<<4) + ((ch) ^ ((row)&7)))           // [*][128] bf16 buffers
#define E16(row, col) ((C16((row),(col)>>3)<<3) + ((col)&7))

__device__ __forceinline__ f32x4 mfma16(short8 a, short8 b, f32x4 c){
    return __builtin_amdgcn_mfma_f32_16x16x32_bf16(a, b, c, 0, 0, 0);
}
__device__ __forceinline__ short f2bf(float f){
    union { float f; unsigned u; } v; v.f = f;
    unsigned r = v.u + 0x7fffu + ((v.u >> 16) & 1u);
    return (short)(r >> 16);
}
__device__ __forceinline__ float bf2f(short s){
    union { unsigned u; float f; } v; v.u = ((unsigned)(unsigned short)s) << 16;
    return v.f;
}
__device__ __forceinline__ short8 bfrag(const short* __restrict__ W, int K, int ct, int ks, int lane){
    return *(const short8*)(W + (long)(ct*16 + (lane&15))*K + ks*32 + (lane>>4)*8);
}

// ---------------- Prep: convert ALL stage weights to bf16 in ws ----------------
__global__ __launch_bounds__(256) void prep_kernel(
    const float* __restrict__ ent_w, const float* __restrict__ q_w,
    const float* __restrict__ k_w,   const float* __restrict__ v_w,
    const float* __restrict__ meas_w,const float* __restrict__ out_w,
    const float* __restrict__ sp_w,  const float* __restrict__ amp_w,
    const float* __restrict__ ph_w,
    short* __restrict__ dst)
{
    int i = blockIdx.x*256 + threadIdx.x;   // 221184 total
    float v;
    if      (i <  65536) v = ent_w[i];
    else if (i <  81920) v = q_w[i-65536];
    else if (i <  98304) v = k_w[i-81920];
    else if (i < 114688) v = v_w[i-98304];
    else if (i < 180224) v = meas_w[i-114688];
    else if (i < 196608) v = out_w[i-180224];
    else if (i < 212992) v = sp_w[i-196608];
    else if (i < 217088) v = amp_w[i-212992];
    else                 v = ph_w[i-217088];
    dst[i] = f2bf(v);
}

// ---------------- Sort pipeline: counting sort of edges by tgt ----------------
__global__ __launch_bounds__(256) void hist_kernel(const int* __restrict__ eidx, int* __restrict__ hist){
    int i = blockIdx.x*256 + threadIdx.x;
    if (i < EE) atomicAdd(&hist[eidx[EE+i]], 1);
}
__global__ __launch_bounds__(512) void scanA_kernel(const int* __restrict__ hist,
                                                    int* __restrict__ scanv, int* __restrict__ bsum){
    __shared__ int s[512];
    const int tid = threadIdx.x;
    const int i = blockIdx.x*512 + tid;
    int v = hist[i];
    s[tid] = v;
    __syncthreads();
    #pragma unroll
    for (int d=1; d<512; d<<=1){
        int t = (tid>=d) ? s[tid-d] : 0;
        __syncthreads();
        s[tid] += t;
        __syncthreads();
    }
    scanv[i] = s[tid] - v;
    if (tid==511) bsum[blockIdx.x] = s[511];
}
__global__ __launch_bounds__(256) void scanB_kernel(const int* __restrict__ bsum, int* __restrict__ boff){
    __shared__ int s[256];
    const int tid = threadIdx.x;
    int v = (tid<196) ? bsum[tid] : 0;
    s[tid] = v;
    __syncthreads();
    #pragma unroll
    for (int d=1; d<256; d<<=1){
        int t = (tid>=d) ? s[tid-d] : 0;
        __syncthreads();
        s[tid] += t;
        __syncthreads();
    }
    if (tid<196) boff[tid] = s[tid] - v;
}
__global__ __launch_bounds__(256) void scatter_kernel(const int* __restrict__ eidx,
    const int* __restrict__ scanv, const int* __restrict__ boff, int* __restrict__ cnt,
    int* __restrict__ sTgt, int* __restrict__ sSrc)
{
    int i = blockIdx.x*256 + threadIdx.x;
    if (i >= EE) return;
    int t = eidx[EE+i], sv = eidx[i];
    int r = atomicAdd(&cnt[t], 1);
    int pos = scanv[t] + boff[t>>9] + r;
    sTgt[pos] = t; sSrc[pos] = sv;
}

// ---------------- Stage 1: node prep via MFMA, 64 nodes/block ----------------
__global__ __launch_bounds__(512) void node_kernel(
    const float* __restrict__ x,
    const short* __restrict__ wSP, const float* __restrict__ sp_b,
    const float* __restrict__ ln1_g, const float* __restrict__ ln1_b,
    const float* __restrict__ pg,
    const short* __restrict__ wA, const float* __restrict__ amp_b,
    const short* __restrict__ wP, const float* __restrict__ ph_b,
    short* __restrict__ qfb)
{
    __shared__ short xb[64*128];     // bf16, swizzled C16 (16 KB)
    __shared__ float yb[64*132];     // f32 GEMM out / later amp|ph (33.8 KB)
    __shared__ short qsb[64*128];    // bf16 tanh(LN(y)), swizzled (16 KB)
    __shared__ float pgs[64];

    const int tid = threadIdx.x;
    const int lane = tid & 63;
    const int w    = tid >> 6;
    const int l15  = lane & 15;
    const int lj   = (lane >> 4) << 2;
    const int n0   = blockIdx.x * 64;

    if (tid < 64){
        float s = 0.f;
        #pragma unroll
        for (int r=0;r<8;r++) s += pg[r*64 + tid];
        pgs[tid] = s;
    }
    // stage x -> bf16 LDS (64 rows x 16 chunks of 8)
    for (int t = tid; t < 1024; t += 512){
        int e = t >> 4, c8 = t & 15;
        int n = n0 + e; if (n >= NN) n = NN-1;
        const float4* xg = (const float4*)(x + (long)n*128 + c8*8);
        float4 a = xg[0], b = xg[1];
        short8 sv;
        sv[0]=f2bf(a.x); sv[1]=f2bf(a.y); sv[2]=f2bf(a.z); sv[3]=f2bf(a.w);
        sv[4]=f2bf(b.x); sv[5]=f2bf(b.y); sv[6]=f2bf(b.z); sv[7]=f2bf(b.w);
        ((short8*)xb)[C16(e, c8)] = sv;
    }
    __syncthreads();

    const short8* xbv = (const short8*)xb;
    const int col = (w<<4) + l15;

    // ---- sp GEMM: y[64][128] = xb @ wSP^T + sp_b ----
    {
        f32x4 acc[4];
        #pragma unroll
        for (int r=0;r<4;r++) acc[r]=(f32x4){0,0,0,0};
        #pragma unroll
        for (int ks=0; ks<4; ks++){
            short8 bw = bfrag(wSP,128,w,ks,lane);
            #pragma unroll
            for (int r=0;r<4;r++){
                int row = r*16+l15;
                acc[r] = mfma16(xbv[(row<<4) + (((ks<<2)+(lane>>4)) ^ (row&7))], bw, acc[r]);
            }
        }
        float bias = sp_b[col];
        #pragma unroll
        for (int r=0;r<4;r++){
            #pragma unroll
            for (int j=0;j<4;j++)
                yb[(r*16+lj+j)*132 + col] = acc[r][j] + bias;
        }
    }
    __syncthreads();

    // ---- LayerNorm + tanh -> qsb bf16 (8 threads per row, 16 cols each) ----
    {
        const int row = tid >> 3, cs = tid & 7;
        float v[16];
        float s = 0.f, sq = 0.f;
        #pragma unroll
        for (int i=0;i<16;i++){
            v[i] = yb[row*132 + cs*16 + i];
            s += v[i]; sq += v[i]*v[i];
        }
        #pragma unroll
        for (int m=1;m<8;m<<=1){ s += __shfl_xor(s,m); sq += __shfl_xor(sq,m); }
        float mean = s*(1.0f/128.0f);
        float rstd = rsqrtf(sq*(1.0f/128.0f) - mean*mean + 1e-5f);
        short8 s0, s1;
        #pragma unroll
        for (int i=0;i<16;i++){
            int c = cs*16 + i;
            float q = tanhf((v[i]-mean)*rstd*ln1_g[c] + ln1_b[c]);
            if (i<8) s0[i] = f2bf(q); else s1[i-8] = f2bf(q);
        }
        ((short8*)qsb)[C16(row, cs*2  )] = s0;
        ((short8*)qsb)[C16(row, cs*2+1)] = s1;
    }
    __syncthreads();

    // ---- amp / ph GEMMs (waves 0-3: amp from real; waves 4-7: ph from imag) ----
    {
        const short8* qv = (const short8*)qsb;
        const int isPh = w >> 2;          // 0: amp, 1: ph
        const int ct   = w & 3;           // 16-col tile within 64 outputs
        f32x4 a4[4];
        #pragma unroll
        for (int r=0;r<4;r++) a4[r]=(f32x4){0,0,0,0};
        #pragma unroll
        for (int ks=0; ks<2; ks++){
            short8 bw = bfrag(isPh ? wP : wA, 64, ct, ks, lane);
            #pragma unroll
            for (int r=0;r<4;r++){
                int row = r*16+l15;
                int ch = isPh*8 + (ks<<2)+(lane>>4);
                a4[r] = mfma16(qv[(row<<4) + (ch ^ (row&7))], bw, a4[r]);
            }
        }
        const int oc = ct*16 + l15;
        float bs = isPh ? ph_b[oc] : amp_b[oc];
        #pragma unroll
        for (int r=0;r<4;r++){
            #pragma unroll
            for (int j=0;j<4;j++){
                float vv = a4[r][j] + bs;
                float ov = isPh ? tanhf(vv)*3.14159265358979323846f
                                : 1.0f/(1.0f+expf(-vv));
                yb[(r*16+lj+j)*132 + isPh*64 + oc] = ov;   // yb reused: [amp|ph]
            }
        }
    }
    __syncthreads();

    // ---- epilogue: qf = [amp*cos(ang) | amp*sin(ang)] ----
    {
        const int row = tid >> 3, cs = tid & 7;
        const int n = n0 + row;
        short8 outc, outs;
        #pragma unroll
        for (int i=0;i<8;i++){
            int c = cs*8 + i;
            float amp  = yb[row*132 + c];
            float ph   = yb[row*132 + 64 + c];
            float real = bf2f(qsb[E16(row, c)]);
            float ang  = ph + real*pgs[c];
            outc[i] = f2bf(amp * cosf(ang));
            outs[i] = f2bf(amp * sinf(ang));
        }
        if (n < NN){
            *(short8*)(qfb + (long)n*128 + cs*8)      = outc;
            *(short8*)(qfb + (long)n*128 + 64 + cs*8) = outs;
        }
    }
}

// ---------------- Stage 2: per-edge MFMA message, tgt-sorted, LDS-reduced scatter ----------------
// NOTE: no min-occupancy arg on launch_bounds — (512,4) forced VGPR=64 and spilled (rounds 2-4).
__global__ __launch_bounds__(512) void edge_kernel(
    const short* __restrict__ qfb,
    const int* __restrict__ sTgt, const int* __restrict__ sSrc,
    const short* __restrict__ wE, const float* __restrict__ ent_b,
    const short* __restrict__ wQ, const float* __restrict__ q_b,
    const short* __restrict__ wK, const float* __restrict__ k_b,
    const short* __restrict__ wV, const float* __restrict__ v_b,
    const short* __restrict__ wM, const float* __restrict__ meas_b,
    const short* __restrict__ wO, const float* __restrict__ out_b,
    float* __restrict__ agg)
{
    __shared__ short xin[ET][256];
    __shared__ __align__(16) char bufB[ET*132*4];
    __shared__ float swv[ET][4];
    __shared__ int tg[ET];
    __shared__ int srr[ET];
    __shared__ int tgPrevS, tgNextS;

    short* qk1  = (short*)bufB;
    float* msgF = (float*)bufB;

    const int nwg = gridDim.x, orig = blockIdx.x;
    const int qd = nwg>>3, rm = nwg&7, xc = orig&7, oo = orig>>3;
    const int bid = (xc<rm ? xc*(qd+1) : rm*(qd+1)+(xc-rm)*qd) + oo;

    const int tid  = threadIdx.x;
    const int lane = tid & 63;
    const int w    = tid >> 6;
    const long e0  = (long)bid * ET;
    const int l15  = lane & 15;
    const int lj   = (lane >> 4) << 2;

    if (tid < ET) { tg[tid] = sTgt[e0+tid]; srr[tid] = sSrc[e0+tid]; }
    if (tid == 64) tgPrevS = (e0 > 0)      ? sTgt[e0-1]  : -2;
    if (tid == 65) tgNextS = (e0+ET < NPAD)? sTgt[e0+ET] : -2;
    __syncthreads();

    for (int t = tid; t < ET*32; t += 512) {
        int e = t >> 5, c8 = t & 31;
        int node = (c8 < 16) ? tg[e] : srr[e];
        if (node < 0) node = 0;
        short8 val = ((const short8*)(qfb + (long)node*128))[c8 & 15];
        ((short8*)&xin[0][0])[C32(e, c8)] = val;
    }
    __syncthreads();

    const short8* xinv = (const short8*)&xin[0][0];
    const int col = (w<<4) + l15;

    // ---- Phase Q ----
    {
        f32x4 aq[4];
        #pragma unroll
        for (int r=0;r<4;r++) aq[r]=(f32x4){0,0,0,0};
        #pragma unroll
        for (int ks=0; ks<4; ks++){
            short8 bq = bfrag(wQ,128,w,ks,lane);
            #pragma unroll
            for (int r=0;r<4;r++)
                aq[r] = mfma16(xinv[C32(r*16+l15, (ks<<2)+(lane>>4))], bq, aq[r]);
        }
        float qbias = q_b[col];
        #pragma unroll
        for (int r=0;r<4;r++){
            #pragma unroll
            for (int j=0;j<4;j++)
                qk1[E32(r*16+lj+j, col)] = f2bf(aq[r][j] + qbias);
        }
    }
    // ---- Phase K ----
    {
        f32x4 ak[4];
        #pragma unroll
        for (int r=0;r<4;r++) ak[r]=(f32x4){0,0,0,0};
        #pragma unroll
        for (int ks=0; ks<4; ks++){
            short8 bk = bfrag(wK,128,w,ks,lane);
            #pragma unroll
            for (int r=0;r<4;r++)
                ak[r] = mfma16(xinv[C32(r*16+l15, 16+(ks<<2)+(lane>>4))], bk, ak[r]);
        }
        float kbias = k_b[col];
        #pragma unroll
        for (int r=0;r<4;r++){
            #pragma unroll
            for (int j=0;j<4;j++)
                qk1[E32(r*16+lj+j, 128+col)] = f2bf(ak[r][j] + kbias);
        }
    }
    __syncthreads();

    // ---- scores + softmax over 4 heads ----
    if (tid < 256){
        int e = tid >> 2, h = tid & 3;
        float s = 0.f;
        #pragma unroll
        for (int d=0; d<32; d++)
            s += bf2f(qk1[E32(e, h*32+d)]) * bf2f(qk1[E32(e, 128+h*32+d)]);
        swv[e][h] = s * 0.17677669529663688f;
    }
    __syncthreads();
    if (tid < ET){
        float s0=swv[tid][0], s1=swv[tid][1], s2=swv[tid][2], s3=swv[tid][3];
        float mx = fmaxf(fmaxf(s0,s1),fmaxf(s2,s3));
        s0=expf(s0-mx); s1=expf(s1-mx); s2=expf(s2-mx); s3=expf(s3-mx);
        float inv = 1.0f/(s0+s1+s2+s3);
        swv[tid][0]=s0*inv; swv[tid][1]=s1*inv; swv[tid][2]=s2*inv; swv[tid][3]=s3*inv;
    }
    __syncthreads();

    // ---- Phase ENT (two 16-col halves) ----
    #pragma unroll 1
    for (int half=0; half<2; half++){
        const int ct = 2*w + half;
        f32x4 a0[4];
        #pragma unroll
        for (int r=0;r<4;r++) a0[r]=(f32x4){0,0,0,0};
        #pragma unroll
        for (int ks=0; ks<8; ks++){
            short8 b0 = bfrag(wE,256,ct,ks,lane);
            #pragma unroll
            for (int r=0;r<4;r++)
                a0[r] = mfma16(xinv[C32(r*16+l15, (ks<<2)+(lane>>4))], b0, a0[r]);
        }
        float bb = ent_b[ct*16 + l15];
        #pragma unroll
        for (int r=0;r<4;r++){
            #pragma unroll
            for (int j=0;j<4;j++)
                qk1[E32(r*16+lj+j, ct*16+l15)] = f2bf(a0[r][j] + bb);
        }
    }
    __syncthreads();

    // ---- Phase V ----
    f32x4 qm[4];
    {
        #pragma unroll
        for (int r=0;r<4;r++) qm[r]=(f32x4){0,0,0,0};
        #pragma unroll
        for (int ks=0; ks<4; ks++){
            short8 bv = bfrag(wV,128,w,ks,lane);
            #pragma unroll
            for (int r=0;r<4;r++)
                qm[r] = mfma16(xinv[C32(r*16+l15, 16+(ks<<2)+(lane>>4))], bv, qm[r]);
        }
        float vbias = v_b[col];
        const int h = w >> 1;
        #pragma unroll
        for (int r=0;r<4;r++){
            #pragma unroll
            for (int j=0;j<4;j++)
                qm[r][j] = (qm[r][j] + vbias) * swv[r*16+lj+j][h];
        }
    }

    // ---- Phase MEAS ----
    {
        const short8* ebv = (const short8*)qk1;
        #pragma unroll 1
        for (int kk=0; kk<4; kk++){
            short8 bm[4];
            const short* wMk = wM + (long)kk*128*128;
            #pragma unroll
            for (int ks=0;ks<4;ks++) bm[ks] = bfrag(wMk, 128, w, ks, lane);
            float mb = meas_b[kk*128 + col];
            #pragma unroll
            for (int r=0;r<4;r++){
                f32x4 mi=(f32x4){0,0,0,0}, mj=(f32x4){0,0,0,0};
                #pragma unroll
                for (int ks=0;ks<4;ks++)
                    mi = mfma16(ebv[C32(r*16+l15, (ks<<2)+(lane>>4))], bm[ks], mi);
                #pragma unroll
                for (int ks=0;ks<4;ks++)
                    mj = mfma16(ebv[C32(r*16+l15, 16+(ks<<2)+(lane>>4))], bm[ks], mj);
                #pragma unroll
                for (int j=0;j<4;j++)
                    qm[r][j] += 0.25f*(mi[j]+mb)*(mj[j]+mb);
            }
        }
    }
    __syncthreads();

    // ---- write msg-in bf16 into msgb (overlaps xin) ----
    short* msgb = &xin[0][0];
    {
        #pragma unroll
        for (int r=0;r<4;r++){
            #pragma unroll
            for (int j=0;j<4;j++){
                int row = r*16 + lj + j;
                int ch = (col>>3) ^ (row&7);
                msgb[((row<<4)+ch)*8 + (col&7)] = f2bf(qm[r][j]);
            }
        }
    }
    __syncthreads();

    // ---- Phase OUT ----
    {
        const short8* mv = (const short8*)msgb;
        f32x4 ao[4];
        #pragma unroll
        for (int r=0;r<4;r++) ao[r]=(f32x4){0,0,0,0};
        #pragma unroll
        for (int ks=0; ks<4; ks++){
            short8 bo = bfrag(wO,128,w,ks,lane);
            #pragma unroll
            for (int r=0;r<4;r++){
                int row = r*16+l15;
                int ch = ((ks<<2)+(lane>>4)) ^ (row&7);
                ao[r] = mfma16(mv[(row<<4)+ch], bo, ao[r]);
            }
        }
        float ob = out_b[col];
        #pragma unroll
        for (int r=0;r<4;r++){
            #pragma unroll
            for (int j=0;j<4;j++)
                msgF[(r*16+lj+j)*132 + col] = ao[r][j] + ob;
        }
    }
    __syncthreads();

    // ---- per-tile segmented reduction over sorted tgt runs ----
    if (tid < 128){
        const int c = tid;
        const int tgPrev = tgPrevS, tgNext = tgNextS;
        float acc = 0.f;
        int runStart = 0;
        #pragma unroll 1
        for (int r=0; r<ET; r++){
            acc += msgF[r*132 + c];
            bool last = (r==ET-1) || (tg[r+1] != tg[r]);
            if (last){
                int node = tg[r];
                if (node >= 0){
                    bool openL = (runStart==0) && (tgPrev == node);
                    bool openR = (r==ET-1)     && (tgNext == node);
                    if (openL || openR) atomicAdd(&agg[(long)node*128 + c], acc);
                    else                agg[(long)node*128 + c] = acc;
                }
                acc = 0.f; runStart = r+1;
            }
        }
    }
}

// ---------------- Stage 3: LN + exact gelu, in place on d_out ----------------
__global__ __launch_bounds__(256) void final_kernel(
    const float* __restrict__ g2, const float* __restrict__ b2,
    float* __restrict__ io)
{
    const int lane = threadIdx.x & 63;
    const int n = blockIdx.x*4 + (threadIdx.x>>6);
    float v0 = io[(long)n*128 + lane];
    float v1 = io[(long)n*128 + 64 + lane];
    float s = v0+v1, sq = v0*v0 + v1*v1;
    #pragma unroll
    for (int m=1;m<64;m<<=1){ s += __shfl_xor(s,m); sq += __shfl_xor(sq,m); }
    float mean = s*(1.0f/128.0f);
    float rstd = rsqrtf(sq*(1.0f/128.0f)-mean*mean+1e-5f);
    float y0 = (v0-mean)*rstd*g2[lane]    + b2[lane];
    float y1 = (v1-mean)*rstd*g2[64+lane] + b2[64+lane];
    io[(long)n*128+lane]    = 0.5f*y0*(1.0f+erff(y0*0.70710678118f));
    io[(long)n*128+64+lane] = 0.5f*y1*(1.0f+erff(y1*0.70710678118f));
}

extern "C" void kernel_launch(void* const* d_in, const int* in_sizes, int n_in,
                              void* d_out, int out_size, void* d_ws, size_t ws_size,
                              hipStream_t stream)
{
    const float* x      = (const float*)d_in[0];
    const int*   eidx   = (const int*)  d_in[1];
    const float* sp_w   = (const float*)d_in[2];
    const float* sp_b   = (const float*)d_in[3];
    const float* ln1_g  = (const float*)d_in[4];
    const float* ln1_b  = (const float*)d_in[5];
    const float* pg     = (const float*)d_in[6];
    const float* amp_w  = (const float*)d_in[7];
    const float* amp_b  = (const float*)d_in[8];
    const float* ph_w   = (const float*)d_in[9];
    const float* ph_b   = (const float*)d_in[10];
    const float* ent_w  = (const float*)d_in[11];
    const float* ent_b  = (const float*)d_in[12];
    const float* q_w    = (const float*)d_in[13];
    const float* q_b    = (const float*)d_in[14];
    const float* k_w    = (const float*)d_in[15];
    const float* k_b    = (const float*)d_in[16];
    const float* v_w    = (const float*)d_in[17];
    const float* v_b    = (const float*)d_in[18];
    const float* meas_w = (const float*)d_in[19];
    const float* meas_b = (const float*)d_in[20];
    const float* out_w  = (const float*)d_in[21];
    const float* out_b  = (const float*)d_in[22];
    const float* ln2_g  = (const float*)d_in[23];
    const float* ln2_b  = (const float*)d_in[24];

    char* wsb = (char*)d_ws;
    short* qfb  = (short*)wsb;                      // 25,600,000 B
    short* wAll = (short*)(wsb + 25600000);         //    442,368 B (221184 bf16)
    int* hist   = (int*)(wsb + 26042368);           //    401,408 B
    int* cnt    = (int*)(wsb + 26443776);           //    401,408 B
    int* scanv  = (int*)(wsb + 26845184);           //    401,408 B
    int* bsum   = (int*)(wsb + 27246592);           //      1,024 B
    int* boff   = (int*)(wsb + 27247616);           //      1,024 B
    int* sTgt   = (int*)(wsb + 27248640);           //  2,000,128 B
    int* sSrc   = (int*)(wsb + 29248768);           //  2,000,128 B -> 31.25 MB

    short* wE  = wAll;                              // 256*256
    short* wQ  = wE + 65536;                        // 128*128
    short* wK  = wQ + 16384;
    short* wV  = wK + 16384;
    short* wM  = wV + 16384;                        // 4*128*128
    short* wO  = wM + 65536;                        // 128*128
    short* wSP = wO + 16384;                        // 128*128
    short* wA  = wSP + 16384;                       // 64*64
    short* wP  = wA + 4096;                         // 64*64

    float* agg = (float*)d_out;

    hipMemsetAsync(d_out, 0, (size_t)NN*128*sizeof(float), stream);
    hipMemsetAsync(hist, 0, 401408, stream);
    hipMemsetAsync(cnt,  0, 401408, stream);
    hipMemsetAsync(sTgt + EE, 0xFF, (NPAD-EE)*sizeof(int), stream);
    hipMemsetAsync(sSrc + EE, 0x00, (NPAD-EE)*sizeof(int), stream);

    prep_kernel<<<864, 256, 0, stream>>>(ent_w, q_w, k_w, v_w, meas_w, out_w,
                                         sp_w, amp_w, ph_w, wAll);
    node_kernel<<<NNB, 512, 0, stream>>>(x, wSP, sp_b, ln1_g, ln1_b, pg,
                                         wA, amp_b, wP, ph_b, qfb);
    hist_kernel<<<(EE+255)/256, 256, 0, stream>>>(eidx, hist);
    scanA_kernel<<<196, 512, 0, stream>>>(hist, scanv, bsum);
    scanB_kernel<<<1, 256, 0, stream>>>(bsum, boff);
    scatter_kernel<<<(EE+255)/256, 256, 0, stream>>>(eidx, scanv, boff, cnt, sTgt, sSrc);
    edge_kernel<<<NEB, 512, 0, stream>>>(qfb, sTgt, sSrc,
                                         wE, ent_b, wQ, q_b, wK, k_b, wV, v_b,
                                         wM, meas_b, wO, out_b, agg);
    final_kernel<<<NN/4, 256, 0, stream>>>(ln2_g, ln2_b, agg);
}